// Round 12
// baseline (614.356 us; speedup 1.0000x reference)
//
#include <hip/hip_runtime.h>
#include <hip/hip_bf16.h>
#include <stdint.h>

// Shapes: B=32, L=256, D=1024, ALIGN=1024, FF=2048, NC=3
// Precision plan:
//  - F proj (split bf16x3), E scores (split bf16x3): the softmax-sensitive path
//  - attn, betas/alphas: fp16 single, V = tanh(Cat@W_G): fp16 single + colsum
//  - classifier: fp32 VALU skinny GEMM
// Graph: 9 launches. All four MFMA GEMMs use the ring/counted-vmcnt family.

typedef __attribute__((ext_vector_type(8))) short    short8_t;   // 8 bf16
typedef __attribute__((ext_vector_type(4))) float    float4_t;
typedef __attribute__((ext_vector_type(8))) _Float16 half8_t;
typedef __attribute__((ext_vector_type(4))) _Float16 half4_t;
typedef __attribute__((ext_vector_type(2))) _Float16 half2_t;

#define DEVI static __device__ __forceinline__

DEVI short f2bf(float f) {
  union { float f; unsigned u; } v; v.f = f;
  unsigned r = v.u + 0x7fffu + ((v.u >> 16) & 1u);   // RNE
  return (short)(r >> 16);
}
DEVI float bf2f(short s) {
  union { unsigned u; float f; } v;
  v.u = ((unsigned)(unsigned short)s) << 16;
  return v.f;
}
DEVI void split2(float x, short& hi, short& lo) {
  hi = f2bf(x);
  lo = f2bf(x - bf2f(hi));
}
DEVI float fast_tanh(float x) {
  float e = __expf(2.0f * x);
  return 1.0f - 2.0f / (e + 1.0f);
}
DEVI void gload16(const void* g, void* l) {
  // async global->LDS, 16B/lane; LDS dest = wave-uniform base + lane*16
  __builtin_amdgcn_global_load_lds(
      (const __attribute__((address_space(1))) void*)g,
      (__attribute__((address_space(3))) void*)l, 16, 0, 0);
}

// ---------------------------------------------------------------------------
// F-projection GEMM: split-bf16x3 NT, 128x256 tile, 512 threads = 8 waves
// (2M x 4N), BK=32, ring-3 LDS (3 x 48 KiB), tile t+2 staged during tile t,
// ONE barrier per tile, counted vmcnt(6), single tail vmcnt(0).
// LDS buffer (shorts): flat 768 row-planes of 32:
//   [0,128)=Ah rows, [128,256)=Al, [256,512)=Bh, [512,768)=Bl
// Chunk swizzle: source chunk (l&3)^((l>>3)&3) => slot s of row r holds
// chunk s^((r>>1)&3); reads at slot q^((m15>>1)&3).
// Block swizzle: by = id&3 -> 4 consecutive blocks share the A panel (L2).
// Epilogue: tanh + split2 store to F_h/F_l [16384][1024].
// ---------------------------------------------------------------------------
__global__ __launch_bounds__(512, 2) void gemm_split_f(
    const short* __restrict__ Ah, const short* __restrict__ Al,
    const short* __restrict__ Bh, const short* __restrict__ Bl,
    short* __restrict__ Fh, short* __restrict__ Fl)
{
  __shared__ __align__(16) short LDS[3][24576];   // 3 x 48 KiB

  const int id   = blockIdx.x;
  const int row0 = (id >> 2) * 128;               // over M=16384
  const int col0 = (id & 3) * 256;                // over N=1024
  const int tid  = threadIdx.x;
  const int lane = tid & 63, wave = tid >> 6;
  const int wr = wave >> 2, wc = wave & 3;        // 2 M-waves x 4 N-waves
  const int m15 = lane & 15, q = lane >> 4;
  const int nt = 1024 / 32;                       // 32 K-tiles

  const int cg = ((lane & 3) ^ ((lane >> 3) & 3)) * 8;
  const short* gptr[6];
  int ldsoff[6];
#pragma unroll
  for (int c = 0; c < 6; ++c) {
    const int f0 = wave * 96 + c * 16;
    const int fr = f0 + (lane >> 2);
    const short* base;
    size_t roff;
    if (f0 < 128)      { base = Ah; roff = (size_t)(row0 + fr) * 1024; }
    else if (f0 < 256) { base = Al; roff = (size_t)(row0 + fr - 128) * 1024; }
    else if (f0 < 512) { base = Bh; roff = (size_t)(col0 + fr - 256) * 1024; }
    else               { base = Bl; roff = (size_t)(col0 + fr - 512) * 1024; }
    gptr[c]   = base + roff + cg;
    ldsoff[c] = f0 * 32;
  }
  auto stage = [&](short* slotbase, int kt) {
#pragma unroll
    for (int c = 0; c < 6; ++c)
      gload16(gptr[c] + kt * 32, slotbase + ldsoff[c]);
  };

  const int xq = (q ^ ((m15 >> 1) & 3)) * 8;
  int arow[4], brow[4];
#pragma unroll
  for (int i = 0; i < 4; ++i) {
    arow[i] = (wr * 64 + i * 16 + m15) * 32 + xq;          // Ah base 0, Al +4096
    brow[i] = 8192 + (wc * 64 + i * 16 + m15) * 32 + xq;   // Bh base, Bl +8192
  }

  float4_t acc[4][4];
#pragma unroll
  for (int i = 0; i < 4; ++i)
#pragma unroll
    for (int j = 0; j < 4; ++j) acc[i][j] = (float4_t)0.0f;

  stage(&LDS[0][0], 0);
  stage(&LDS[1][0], 1);
  asm volatile("s_waitcnt vmcnt(6)");
  __builtin_amdgcn_s_barrier();

  int cur = 0, st2 = 2;
  for (int t = 0; t < nt; ++t) {
    short* buf = &LDS[cur][0];
    __builtin_amdgcn_sched_barrier(0);

    short8_t ah[4], al[4], bh[4], bl[4];
#pragma unroll
    for (int i = 0; i < 4; ++i) {
      ah[i] = *(const short8_t*)&buf[arow[i]];
      al[i] = *(const short8_t*)&buf[arow[i] + 4096];
    }
#pragma unroll
    for (int j = 0; j < 4; ++j) {
      bh[j] = *(const short8_t*)&buf[brow[j]];
      bl[j] = *(const short8_t*)&buf[brow[j] + 8192];
    }

    if (t + 2 < nt) stage(&LDS[st2][0], t + 2);

    __builtin_amdgcn_s_setprio(1);
#pragma unroll
    for (int i = 0; i < 4; ++i)
#pragma unroll
      for (int j = 0; j < 4; ++j) {
        acc[i][j] = __builtin_amdgcn_mfma_f32_16x16x32_bf16(ah[i], bh[j], acc[i][j], 0, 0, 0);
        acc[i][j] = __builtin_amdgcn_mfma_f32_16x16x32_bf16(ah[i], bl[j], acc[i][j], 0, 0, 0);
        acc[i][j] = __builtin_amdgcn_mfma_f32_16x16x32_bf16(al[i], bh[j], acc[i][j], 0, 0, 0);
      }
    __builtin_amdgcn_s_setprio(0);

    __builtin_amdgcn_sched_barrier(0);
    if (t + 2 < nt) {
      asm volatile("s_waitcnt vmcnt(6)");
    } else if (t + 1 < nt) {
      asm volatile("s_waitcnt vmcnt(0)");
    }
    __builtin_amdgcn_s_barrier();
    cur = (cur == 2) ? 0 : cur + 1;
    st2 = (st2 == 2) ? 0 : st2 + 1;
  }

#pragma unroll
  for (int i = 0; i < 4; ++i) {
#pragma unroll
    for (int r = 0; r < 4; ++r) {
      const int gm = row0 + wr * 64 + i * 16 + q * 4 + r;
#pragma unroll
      for (int j = 0; j < 4; ++j) {
        const int gn = col0 + wc * 64 + j * 16 + m15;
        float v = fast_tanh(acc[i][j][r]);
        short hi, lo; split2(v, hi, lo);
        Fh[(size_t)gm * 1024 + gn] = hi;
        Fl[(size_t)gm * 1024 + gn] = lo;
      }
    }
  }
}

// ---------------------------------------------------------------------------
// E-scores GEMM: same ring-3 body as gemm_split_f, nt=8. Grid 256 blocks:
// zb = id>>3 (batch), sp = (id>>2)&1 (M-half), zk = id&3 (k-slice).
// Epilogue: plain fp32 store to eparts panel (zb*4+zk) [256][256].
// ---------------------------------------------------------------------------
__global__ __launch_bounds__(512, 2) void gemm_split_e(
    const short* __restrict__ Fh, const short* __restrict__ Fl,
    float* __restrict__ eparts)
{
  __shared__ __align__(16) short LDS[3][24576];

  const int id = blockIdx.x;
  const int zb = id >> 3;
  const int sp = (id >> 2) & 1;
  const int zk = id & 3;
  const int arow0 = zb * 256 + sp * 128;
  const int brow0 = 8192 + zb * 256;
  const int kbeg  = zk * 256;
  const int tid = threadIdx.x, lane = tid & 63, wave = tid >> 6;
  const int wr = wave >> 2, wc = wave & 3;
  const int m15 = lane & 15, q = lane >> 4;
  const int nt = 8;

  const int cg = ((lane & 3) ^ ((lane >> 3) & 3)) * 8;
  const short* gptr[6];
  int ldsoff[6];
#pragma unroll
  for (int c = 0; c < 6; ++c) {
    const int f0 = wave * 96 + c * 16;
    const int fr = f0 + (lane >> 2);
    const short* base;
    size_t roff;
    if (f0 < 128)      { base = Fh; roff = (size_t)(arow0 + fr) * 1024; }
    else if (f0 < 256) { base = Fl; roff = (size_t)(arow0 + fr - 128) * 1024; }
    else if (f0 < 512) { base = Fh; roff = (size_t)(brow0 + fr - 256) * 1024; }
    else               { base = Fl; roff = (size_t)(brow0 + fr - 512) * 1024; }
    gptr[c]   = base + roff + kbeg + cg;
    ldsoff[c] = f0 * 32;
  }
  auto stage = [&](short* slotbase, int kt) {
#pragma unroll
    for (int c = 0; c < 6; ++c)
      gload16(gptr[c] + kt * 32, slotbase + ldsoff[c]);
  };

  const int xq = (q ^ ((m15 >> 1) & 3)) * 8;
  int arow[4], brow[4];
#pragma unroll
  for (int i = 0; i < 4; ++i) {
    arow[i] = (wr * 64 + i * 16 + m15) * 32 + xq;
    brow[i] = 8192 + (wc * 64 + i * 16 + m15) * 32 + xq;
  }

  float4_t acc[4][4];
#pragma unroll
  for (int i = 0; i < 4; ++i)
#pragma unroll
    for (int j = 0; j < 4; ++j) acc[i][j] = (float4_t)0.0f;

  stage(&LDS[0][0], 0);
  stage(&LDS[1][0], 1);
  asm volatile("s_waitcnt vmcnt(6)");
  __builtin_amdgcn_s_barrier();

  int cur = 0, st2 = 2;
  for (int t = 0; t < nt; ++t) {
    short* buf = &LDS[cur][0];
    __builtin_amdgcn_sched_barrier(0);

    short8_t ah[4], al[4], bh[4], bl[4];
#pragma unroll
    for (int i = 0; i < 4; ++i) {
      ah[i] = *(const short8_t*)&buf[arow[i]];
      al[i] = *(const short8_t*)&buf[arow[i] + 4096];
    }
#pragma unroll
    for (int j = 0; j < 4; ++j) {
      bh[j] = *(const short8_t*)&buf[brow[j]];
      bl[j] = *(const short8_t*)&buf[brow[j] + 8192];
    }

    if (t + 2 < nt) stage(&LDS[st2][0], t + 2);

    __builtin_amdgcn_s_setprio(1);
#pragma unroll
    for (int i = 0; i < 4; ++i)
#pragma unroll
      for (int j = 0; j < 4; ++j) {
        acc[i][j] = __builtin_amdgcn_mfma_f32_16x16x32_bf16(ah[i], bh[j], acc[i][j], 0, 0, 0);
        acc[i][j] = __builtin_amdgcn_mfma_f32_16x16x32_bf16(ah[i], bl[j], acc[i][j], 0, 0, 0);
        acc[i][j] = __builtin_amdgcn_mfma_f32_16x16x32_bf16(al[i], bh[j], acc[i][j], 0, 0, 0);
      }
    __builtin_amdgcn_s_setprio(0);

    __builtin_amdgcn_sched_barrier(0);
    if (t + 2 < nt) {
      asm volatile("s_waitcnt vmcnt(6)");
    } else if (t + 1 < nt) {
      asm volatile("s_waitcnt vmcnt(0)");
    }
    __builtin_amdgcn_s_barrier();
    cur = (cur == 2) ? 0 : cur + 1;
    st2 = (st2 == 2) ? 0 : st2 + 1;
  }

  float* ep = eparts + (size_t)(zb * 4 + zk) * 65536;
#pragma unroll
  for (int i = 0; i < 4; ++i) {
#pragma unroll
    for (int r = 0; r < 4; ++r) {
      const int gm = sp * 128 + wr * 64 + i * 16 + q * 4 + r;
#pragma unroll
      for (int j = 0; j < 4; ++j) {
        const int gn = wc * 64 + j * 16 + m15;
        ep[(size_t)gm * 256 + gn] = acc[i][j][r];
      }
    }
  }
}

// ---------------------------------------------------------------------------
// betas/alphas GEMM: fp16 NT ring-3, 128x256 tile, 512 threads, BK=32,
// 3 x 24 KiB LDS, counted vmcnt(3), nt=8.
// grid (8,1,64): A = attn[z] (z<32) / attnT (z>=32, contiguous);
// B = PHbT[(z^32)] panel. Epilogue: fp16 store to Cat right halves.
// ---------------------------------------------------------------------------
__global__ __launch_bounds__(512, 2) void gemm_f16r(
    const _Float16* __restrict__ attn, const _Float16* __restrict__ phbt,
    _Float16* __restrict__ cat)
{
  __shared__ __align__(16) _Float16 LDS[3][12288];   // 3 x 24 KiB

  const int bx = blockIdx.x;
  const int z  = blockIdx.z;
  const int mt = bx >> 2, ntile = bx & 3;
  const int row0 = mt * 128;
  const int col0 = ntile * 256;
  const _Float16* A = attn + (size_t)z * 65536;
  const _Float16* B = phbt + (size_t)(z ^ 32) * 262144 + (size_t)col0 * 256;
  const int tid = threadIdx.x, lane = tid & 63, wave = tid >> 6;
  const int wr = wave >> 2, wc = wave & 3;
  const int m15 = lane & 15, q = lane >> 4;
  const int nt = 8;

  const int cg = ((lane & 3) ^ ((lane >> 3) & 3)) * 8;
  const _Float16* gptr[3];
  int ldsoff[3];
#pragma unroll
  for (int c = 0; c < 3; ++c) {
    const int f0 = wave * 48 + c * 16;
    const int fr = f0 + (lane >> 2);
    if (f0 < 128) gptr[c] = A + (size_t)(row0 + fr) * 256 + cg;
    else          gptr[c] = B + (size_t)(fr - 128) * 256 + cg;
    ldsoff[c] = f0 * 32;
  }
  auto stage = [&](_Float16* slotbase, int kt) {
#pragma unroll
    for (int c = 0; c < 3; ++c)
      gload16(gptr[c] + kt * 32, slotbase + ldsoff[c]);
  };

  const int xq = (q ^ ((m15 >> 1) & 3)) * 8;
  int aoff[4], boff[4];
#pragma unroll
  for (int i = 0; i < 4; ++i) {
    aoff[i] = (wr * 64 + i * 16 + m15) * 32 + xq;
    boff[i] = (128 + wc * 64 + i * 16 + m15) * 32 + xq;
  }

  float4_t acc[4][4];
#pragma unroll
  for (int i = 0; i < 4; ++i)
#pragma unroll
    for (int j = 0; j < 4; ++j) acc[i][j] = (float4_t)0.0f;

  stage(&LDS[0][0], 0);
  stage(&LDS[1][0], 1);
  asm volatile("s_waitcnt vmcnt(3)");
  __builtin_amdgcn_s_barrier();

  int cur = 0, st2 = 2;
  for (int t = 0; t < nt; ++t) {
    _Float16* buf = &LDS[cur][0];
    __builtin_amdgcn_sched_barrier(0);

    half8_t af[4], bf[4];
#pragma unroll
    for (int i = 0; i < 4; ++i) af[i] = *(const half8_t*)&buf[aoff[i]];
#pragma unroll
    for (int j = 0; j < 4; ++j) bf[j] = *(const half8_t*)&buf[boff[j]];

    if (t + 2 < nt) stage(&LDS[st2][0], t + 2);

    __builtin_amdgcn_s_setprio(1);
#pragma unroll
    for (int i = 0; i < 4; ++i)
#pragma unroll
      for (int j = 0; j < 4; ++j)
        acc[i][j] = __builtin_amdgcn_mfma_f32_16x16x32_f16(af[i], bf[j], acc[i][j], 0, 0, 0);
    __builtin_amdgcn_s_setprio(0);

    __builtin_amdgcn_sched_barrier(0);
    if (t + 2 < nt) {
      asm volatile("s_waitcnt vmcnt(3)");
    } else if (t + 1 < nt) {
      asm volatile("s_waitcnt vmcnt(0)");
    }
    __builtin_amdgcn_s_barrier();
    cur = (cur == 2) ? 0 : cur + 1;
    st2 = (st2 == 2) ? 0 : st2 + 1;
  }

  _Float16* Cp = cat + 1024 + (size_t)z * (256 * 2048);
#pragma unroll
  for (int i = 0; i < 4; ++i) {
#pragma unroll
    for (int r = 0; r < 4; ++r) {
      const int gm = row0 + wr * 64 + i * 16 + q * 4 + r;
#pragma unroll
      for (int j = 0; j < 4; ++j) {
        const int gn = col0 + wc * 64 + j * 16 + m15;
        Cp[(size_t)gm * 2048 + gn] = (_Float16)acc[i][j][r];
      }
    }
  }
}

// ---------------------------------------------------------------------------
// V-GEMM: fp16 NT, 256x256 tile, BK=32, 512 threads = 8 waves (2M x 4N),
// 4-deep LDS ring (4 x 32 KiB), tile t+2 staged during tile t, ONE barrier
// per K-tile, counted vmcnt(4). Conflict-free chunk swizzle (0 measured).
// Fused tanh + column-sum epilogue -> agg. (141-161 us band, 43-44% MfmaUtil;
// LDS-read-port + sync-bound — frozen at the free-run-ring family ceiling.)
// ---------------------------------------------------------------------------
__global__ __launch_bounds__(512, 2) void gemm_f16_sum8(
    const _Float16* __restrict__ A, int lda,
    const _Float16* __restrict__ B, int ldb,
    int K, float* __restrict__ agg)
{
  __shared__ __align__(16) _Float16 LDS[4][2 * 256 * 32];

  const int row0 = blockIdx.x * 256;
  const int col0 = blockIdx.y * 256;
  const int tid  = threadIdx.x;
  const int lane = tid & 63, wave = tid >> 6;
  const int wr = wave >> 2, wc = wave & 3;     // 2 M-waves x 4 N-waves
  const int m15 = lane & 15, q = lane >> 4;
  const int nt = K / 32;

  const int srow = wave * 32 + (lane >> 2);
  const int cg   = ((lane & 3) ^ ((lane >> 3) & 3)) * 8;
  const _Float16* gA = A + (size_t)(row0 + srow) * lda + cg;
  const _Float16* gB = B + (size_t)(col0 + srow) * ldb + cg;

  auto stageA = [&](int t) {
    const _Float16* g = gA + t * 32;
    _Float16* l = &LDS[t & 3][wave * 1024];
    gload16(g, l);
    gload16(g + (size_t)16 * lda, l + 512);
  };
  auto stageB = [&](int t) {
    const _Float16* g = gB + t * 32;
    _Float16* l = &LDS[t & 3][8192 + wave * 1024];
    gload16(g, l);
    gload16(g + (size_t)16 * ldb, l + 512);
  };

  const int xq = (q ^ ((m15 >> 1) & 3)) * 8;
  int aoff[8], boff[4];
#pragma unroll
  for (int i = 0; i < 8; ++i)
    aoff[i] = (wr * 128 + i * 16 + m15) * 32 + xq;
#pragma unroll
  for (int j = 0; j < 4; ++j)
    boff[j] = 8192 + (wc * 64 + j * 16 + m15) * 32 + xq;

  float4_t acc[8][4];
#pragma unroll
  for (int i = 0; i < 8; ++i)
#pragma unroll
    for (int j = 0; j < 4; ++j) acc[i][j] = (float4_t)0.0f;

  stageA(0); stageB(0);
  stageA(1); stageB(1);
  asm volatile("s_waitcnt vmcnt(4)");
  __builtin_amdgcn_s_barrier();

  for (int t = 0; t < nt; ++t) {
    const _Float16* buf = &LDS[t & 3][0];
    __builtin_amdgcn_sched_barrier(0);

    half8_t a0[4], a1[4], bb[4];
#pragma unroll
    for (int i = 0; i < 4; ++i) a0[i] = *(const half8_t*)&buf[aoff[i]];
#pragma unroll
    for (int j = 0; j < 4; ++j) bb[j] = *(const half8_t*)&buf[boff[j]];
#pragma unroll
    for (int i = 0; i < 4; ++i) a1[i] = *(const half8_t*)&buf[aoff[4 + i]];

    if (t + 2 < nt) { stageA(t + 2); stageB(t + 2); }

    __builtin_amdgcn_s_setprio(1);
#pragma unroll
    for (int i = 0; i < 4; ++i)
#pragma unroll
      for (int j = 0; j < 4; ++j)
        acc[i][j] = __builtin_amdgcn_mfma_f32_16x16x32_f16(a0[i], bb[j], acc[i][j], 0, 0, 0);
#pragma unroll
    for (int i = 0; i < 4; ++i)
#pragma unroll
      for (int j = 0; j < 4; ++j)
        acc[4 + i][j] = __builtin_amdgcn_mfma_f32_16x16x32_f16(a1[i], bb[j], acc[4 + i][j], 0, 0, 0);
    __builtin_amdgcn_s_setprio(0);

    __builtin_amdgcn_sched_barrier(0);
    if (t + 2 < nt) {
      asm volatile("s_waitcnt vmcnt(4)");
    } else if (t + 1 < nt) {
      asm volatile("s_waitcnt vmcnt(0)");
    }
    __builtin_amdgcn_s_barrier();
  }

  // ---- epilogue: tanh + column-sum -> agg[b][half*2048 + col] ----
  const int half_ = row0 >= 8192;
  const int b     = (row0 & 8191) >> 8;
#pragma unroll
  for (int j = 0; j < 4; ++j) {
    float s = 0.0f;
#pragma unroll
    for (int i = 0; i < 8; ++i)
#pragma unroll
      for (int r = 0; r < 4; ++r) s += fast_tanh(acc[i][j][r]);
    s += __shfl_xor(s, 16);
    s += __shfl_xor(s, 32);
    if (q == 0) {
      int col = col0 + wc * 64 + j * 16 + m15;
      atomicAdd(&agg[(size_t)b * 4096 + half_ * 2048 + col], s);
    }
  }
}

// ---------------------------------------------------------------------------
// prep (round 12): merged input-conversion + weight-transposes, one launch.
// Blocks [0,4096): conv_in_t body (vectorized; also zeros agg via blocks
// [0,128)).  Blocks [4096,5120): W_F -> split bf16 transpose.
// Blocks [5120,9216): W_G -> fp16 transpose.
// ---------------------------------------------------------------------------
__global__ __launch_bounds__(256) void prep(
    const float* __restrict__ P, const float* __restrict__ Hh,
    short* __restrict__ oh, short* __restrict__ ol,
    _Float16* __restrict__ cat, _Float16* __restrict__ phbt,
    float* __restrict__ agg,
    const float* __restrict__ WF, short* __restrict__ wfh, short* __restrict__ wfl,
    const float* __restrict__ WG, _Float16* __restrict__ og)
{
  __shared__ __align__(16) float tile[64][68];   // 17.4 KB (covers both uses)
  const int id = blockIdx.x;
  const int t  = threadIdx.x;

  if (id < 4096) {
    // ---- conv_in_t: x = id&15, y = (id>>4)&3, zb = id>>6 ----
    const int zb   = id >> 6;
    const int half = zb >> 5, b = zb & 31;
    if (id < 128) {
      float4_t zz = (float4_t)0.0f;
      *(float4_t*)&agg[(size_t)id * 1024 + t * 4] = zz;
    }
    const float* in = (half ? Hh : P) + (size_t)b * 256 * 1024;
    const int c0 = (id & 15) * 64;        // col in [0,1024)
    const int r0 = ((id >> 4) & 3) * 64;  // row in [0,256)
    const int rl = t >> 4;                // 0..15
    const int c4 = (t & 15) * 4;          // 0,4,...,60
    const size_t rowbase = (size_t)half * 8192 + (size_t)b * 256;
#pragma unroll
    for (int i = 0; i < 4; ++i) {
      int r = rl + i * 16;
      float4 v = *(const float4*)&in[(size_t)(r0 + r) * 1024 + c0 + c4];
      *(float4*)&tile[r][c4] = v;
      short4 h, l;
      split2(v.x, h.x, l.x); split2(v.y, h.y, l.y);
      split2(v.z, h.z, l.z); split2(v.w, h.w, l.w);
      size_t o = (rowbase + r0 + r) * 1024 + c0 + c4;
      *(short4*)&oh[o] = h;
      *(short4*)&ol[o] = l;
      half4_t c16;
      c16.x = (_Float16)v.x; c16.y = (_Float16)v.y;
      c16.z = (_Float16)v.z; c16.w = (_Float16)v.w;
      *(half4_t*)&cat[(rowbase + r0 + r) * 2048 + c0 + c4] = c16;
    }
    __syncthreads();
    _Float16* op = phbt + (size_t)zb * 1024 * 256;
    const int tx = t & 31;                // row-pair index
    const int w  = t >> 5;                // 0..7
#pragma unroll
    for (int i = 0; i < 8; ++i) {
      int cc = w + i * 8;                 // 0..63
      half2_t p;
      p.x = (_Float16)tile[tx * 2][cc];
      p.y = (_Float16)tile[tx * 2 + 1][cc];
      *(half2_t*)&op[(size_t)(c0 + cc) * 256 + r0 + tx * 2] = p;
    }
  } else if (id < 5120) {
    // ---- W_F split transpose: 32x32 tiles over [1024][1024] ----
    const int t2 = id - 4096;
    const int c0 = (t2 & 31) * 32, r0 = (t2 >> 5) * 32;
    const int tx = t & 31, ty = t >> 5;
#pragma unroll
    for (int i = 0; i < 4; ++i) {
      int r = ty + i * 8;
      tile[r][tx] = WF[(size_t)(r0 + r) * 1024 + c0 + tx];
    }
    __syncthreads();
#pragma unroll
    for (int i = 0; i < 4; ++i) {
      int cc = ty + i * 8;
      float v = tile[tx][cc];
      short hi, lo; split2(v, hi, lo);
      size_t o = (size_t)(c0 + cc) * 1024 + r0 + tx;
      wfh[o] = hi;
      wfl[o] = lo;
    }
  } else {
    // ---- W_G fp16 transpose: 32x32 tiles over [2048][2048] ----
    const int t2 = id - 5120;
    const int c0 = (t2 & 63) * 32, r0 = (t2 >> 6) * 32;
    const int tx = t & 31, ty = t >> 5;
#pragma unroll
    for (int i = 0; i < 4; ++i) {
      int r = ty + i * 8;
      tile[r][tx] = WG[(size_t)(r0 + r) * 2048 + c0 + tx];
    }
    __syncthreads();
#pragma unroll
    for (int i = 0; i < 4; ++i) {
      int cc = ty + i * 8;
      og[(size_t)(c0 + cc) * 2048 + r0 + tx] = (_Float16)tile[tx][cc];
    }
  }
}

// ---------------------------------------------------------------------------
// softmax over rows of 256, summing 4 E split-K slice panels, fp32 -> fp16,
// AND writes the batched transpose attnT directly (round 12: kills the
// transpose_b2b launch + its 8 MB of traffic). Block = 4 rows of one batch;
// stash the 4x256 softmaxed row-block in LDS, then thread t gathers column t
// (4 fp16 = 8 B) and stores attnT[z][t][r0..r0+3].
// ---------------------------------------------------------------------------
__global__ __launch_bounds__(256) void softmax_rows(
    const float* __restrict__ e, _Float16* __restrict__ attn,
    _Float16* __restrict__ attnT)
{
  __shared__ _Float16 sm[4][256];
  const int bid  = blockIdx.x;                       // 0..2047
  const int lr   = threadIdx.x >> 6;                 // 0..3 (row within block)
  const int lane = threadIdx.x & 63;
  const int row  = bid * 4 + lr;                     // global row 0..8191
  const size_t base = ((size_t)(row >> 8) * 4) * 65536
                    + (size_t)(row & 255) * 256 + lane * 4;
  const float4 v0 = *(const float4*)&e[base];
  const float4 v1 = *(const float4*)&e[base + 65536];
  const float4 v2 = *(const float4*)&e[base + 2 * 65536];
  const float4 v3 = *(const float4*)&e[base + 3 * 65536];
  float4 v;
  v.x = (v0.x + v1.x) + (v2.x + v3.x);
  v.y = (v0.y + v1.y) + (v2.y + v3.y);
  v.z = (v0.z + v1.z) + (v2.z + v3.z);
  v.w = (v0.w + v1.w) + (v2.w + v3.w);
  float m = fmaxf(fmaxf(v.x, v.y), fmaxf(v.z, v.w));
#pragma unroll
  for (int off = 32; off; off >>= 1) m = fmaxf(m, __shfl_xor(m, off));
  float e0 = __expf(v.x - m), e1 = __expf(v.y - m);
  float e2 = __expf(v.z - m), e3 = __expf(v.w - m);
  float s = e0 + e1 + e2 + e3;
#pragma unroll
  for (int off = 32; off; off >>= 1) s += __shfl_xor(s, off);
  float inv = 1.0f / s;
  half4_t o;
  o.x = (_Float16)(e0 * inv); o.y = (_Float16)(e1 * inv);
  o.z = (_Float16)(e2 * inv); o.w = (_Float16)(e3 * inv);
  *(half4_t*)&attn[(size_t)row * 256 + lane * 4] = o;
  *(half4_t*)&sm[lr][lane * 4] = o;
  __syncthreads();
  const int z  = bid >> 6;                           // batch
  const int r0 = (bid * 4) & 255;                    // row-in-batch base
  const int col = threadIdx.x;
  half4_t tv;
  tv.x = sm[0][col]; tv.y = sm[1][col];
  tv.z = sm[2][col]; tv.w = sm[3][col];
  *(half4_t*)&attnT[(size_t)z * 65536 + (size_t)col * 256 + r0] = tv;
}

// ---------------------------------------------------------------------------
// Skinny fp32 GEMM, split-K per-slice panels (no atomics, no pre-zero):
// outp[slice][32][N] = A[32][k-slice] @ B[k-slice][N].
// grid (N/64, K/256); block 256. A-slice transposed in LDS [k][m] (+1 pad).
// ---------------------------------------------------------------------------
__global__ __launch_bounds__(256) void skinny_gemm(
    const float* __restrict__ A, const float* __restrict__ B,
    float* __restrict__ outp, int N, int K)
{
  __shared__ float Asl[256][33];
  const int n0 = blockIdx.x * 64;
  const int k0 = blockIdx.y * 256;
  const int t  = threadIdx.x;
#pragma unroll
  for (int j = 0; j < 32; ++j) {
    Asl[t][j] = A[(size_t)j * K + k0 + t];
  }
  __syncthreads();
  const int l = t & 63, w = t >> 6;
  const int n = n0 + l;
  float acc[8] = {0.f, 0.f, 0.f, 0.f, 0.f, 0.f, 0.f, 0.f};
  const float* Bp = B + (size_t)k0 * N + n;
#pragma unroll 4
  for (int k = 0; k < 256; ++k) {
    float bv = Bp[(size_t)k * N];
#pragma unroll
    for (int m = 0; m < 8; ++m)
      acc[m] += Asl[k][w * 8 + m] * bv;
  }
  float* o = outp + (size_t)blockIdx.y * 32 * N;
#pragma unroll
  for (int m = 0; m < 8; ++m)
    o[(size_t)(w * 8 + m) * N + n] = acc[m];
}

// ---------------------------------------------------------------------------
// Skinny fp32 GEMM with inline A = tanh(sum_16(c1parts) + b1) (round 12:
// kills the bias_sum_tanh launch; c1parts (4 MB) is L2-resident).
// outp[slice][32][N] = a1[32][k-slice] @ W2[k-slice][N]; K = N = 2048.
// ---------------------------------------------------------------------------
__global__ __launch_bounds__(256) void skinny_gemm_a1(
    const float* __restrict__ c1parts, const float* __restrict__ b1,
    const float* __restrict__ B, float* __restrict__ outp, int N, int K)
{
  __shared__ float Asl[256][33];
  const int n0 = blockIdx.x * 64;
  const int k0 = blockIdx.y * 256;
  const int t  = threadIdx.x;
  const float bb = b1[k0 + t];
#pragma unroll
  for (int j = 0; j < 32; ++j) {
    float s = 0.0f;
#pragma unroll
    for (int sl = 0; sl < 16; ++sl)
      s += c1parts[(size_t)sl * 65536 + (size_t)j * 2048 + k0 + t];
    Asl[t][j] = fast_tanh(s + bb);
  }
  __syncthreads();
  const int l = t & 63, w = t >> 6;
  const int n = n0 + l;
  float acc[8] = {0.f, 0.f, 0.f, 0.f, 0.f, 0.f, 0.f, 0.f};
  const float* Bp = B + (size_t)k0 * N + n;
#pragma unroll 4
  for (int k = 0; k < 256; ++k) {
    float bv = Bp[(size_t)k * N];
#pragma unroll
    for (int m = 0; m < 8; ++m)
      acc[m] += Asl[k][w * 8 + m] * bv;
  }
  float* o = outp + (size_t)blockIdx.y * 32 * N;
#pragma unroll
  for (int m = 0; m < 8; ++m)
    o[(size_t)(w * 8 + m) * N + n] = acc[m];
}

// --- logits: out[b][0..2] = tanh(sum_8slices(c2parts)[b]+b2) @ W3 + b3 ---
__global__ __launch_bounds__(256) void logits2(
    const float* __restrict__ c2parts, const float* __restrict__ b2,
    const float* __restrict__ W3, const float* __restrict__ b3,
    float* __restrict__ out)
{
  const int b = blockIdx.x, t = threadIdx.x;
  float p0 = 0.f, p1 = 0.f, p2 = 0.f;
  for (int k = t; k < 2048; k += 256) {
    float c = 0.0f;
#pragma unroll
    for (int sl = 0; sl < 8; ++sl) c += c2parts[(size_t)sl * 65536 + b * 2048 + k];
    float a = fast_tanh(c + b2[k]);
    p0 += a * W3[k * 3 + 0];
    p1 += a * W3[k * 3 + 1];
    p2 += a * W3[k * 3 + 2];
  }
#pragma unroll
  for (int off = 32; off; off >>= 1) {
    p0 += __shfl_xor(p0, off);
    p1 += __shfl_xor(p1, off);
    p2 += __shfl_xor(p2, off);
  }
  __shared__ float red[4][3];
  if ((t & 63) == 0) {
    red[t >> 6][0] = p0; red[t >> 6][1] = p1; red[t >> 6][2] = p2;
  }
  __syncthreads();
  if (t < 3) out[b * 3 + t] = b3[t] + red[0][t] + red[1][t] + red[2][t] + red[3][t];
}

extern "C" void kernel_launch(void* const* d_in, const int* in_sizes, int n_in,
                              void* d_out, int out_size, void* d_ws, size_t ws_size,
                              hipStream_t stream) {
  (void)in_sizes; (void)n_in; (void)out_size; (void)ws_size;
  const float* P   = (const float*)d_in[0];
  const float* H   = (const float*)d_in[1];
  const float* W_F = (const float*)d_in[2];
  const float* W_G = (const float*)d_in[3];
  const float* W1  = (const float*)d_in[4];
  const float* b1  = (const float*)d_in[5];
  const float* W2  = (const float*)d_in[6];
  const float* b2  = (const float*)d_in[7];
  const float* W3  = (const float*)d_in[8];
  const float* b3  = (const float*)d_in[9];
  float* out = (float*)d_out;

  char* wsp = (char*)d_ws;
  auto alloc = [&](size_t bytes) {
    char* p = wsp;
    wsp += (bytes + 255) & ~(size_t)255;
    return p;
  };
  short*    Pp_h  = (short*)alloc(16384ull * 1024 * 2);     // [P;H] split planes
  short*    Pp_l  = (short*)alloc(16384ull * 1024 * 2);
  _Float16* Cat16 = (_Float16*)alloc(16384ull * 2048 * 2);  // [P|betas ; H|alphas]
  short*    Fbuf  = (short*)alloc(32ull * 1024 * 1024 * 2); // 64 MB: F planes
  _Float16* PHbT  = (_Float16*)alloc(64ull * 1024 * 256 * 2); // 32 MB: P^T|H^T fp16
  short*    WFT_h = (short*)alloc(1024ull * 1024 * 2);
  short*    WFT_l = (short*)alloc(1024ull * 1024 * 2);
  _Float16* WGT16 = (_Float16*)alloc(2048ull * 2048 * 2);
  _Float16* attn  = (_Float16*)alloc(32ull * 256 * 256 * 2);  // adjacent pair:
  _Float16* attnT = (_Float16*)alloc(32ull * 256 * 256 * 2);  // f16r reads both
  float*    agg   = (float*)alloc(32ull * 4096 * 4);

  short* F_h = Fbuf;
  short* F_l = Fbuf + 16384ull * 1024;
  // Aliases into Pp planes (dead after the F-projection, step 2):
  float* eparts  = (float*)Pp_h;                       // 32 MB <= 33.5 MB
  float* c1parts = (float*)Pp_l;                       // 16 x 32 x 2048 fp32
  float* c2parts = (float*)(Pp_l + 4ull * 1024 * 1024);// 8 x 32 x 2048 fp32

  // 1. prep: input conversion + per-batch transpose + agg zero + W transposes
  prep<<<9216, 256, 0, stream>>>(P, H, Pp_h, Pp_l, Cat16, PHbT, agg,
                                 W_F, WFT_h, WFT_l, W_G, WGT16);

  // 2. F = tanh([P;H] @ W_F), split bf16x3, ring-3 counted-vmcnt kernel
  gemm_split_f<<<512, 512, 0, stream>>>(Pp_h, Pp_l, WFT_h, WFT_l, F_h, F_l);

  // 3. scores E[z] = F_p[z] @ F_h[z]^T, ring-3, split-K x4 slice panels
  gemm_split_e<<<256, 512, 0, stream>>>(F_h, F_l, eparts);

  // 4. softmax (sums 4 E slices) -> fp16 attn AND attnT (fused transpose)
  softmax_rows<<<2048, 256, 0, stream>>>(eparts, attn, attnT);

  // 5. betas (z<32) and alphas (z>=32) in ONE launch, ring-3 fp16 kernel
  gemm_f16r<<<dim3(8, 1, 64), 512, 0, stream>>>(attn, PHbT, Cat16);

  // 6. V = tanh(Cat @ W_G) fused column-sum -> agg
  gemm_f16_sum8<<<dim3(64, 8, 1), 512, 0, stream>>>(
      Cat16, 2048, WGT16, 2048, 2048, agg);

  // 7. classifier: fp32 skinny split-K GEMMs; a1 computed inline in stage 2
  skinny_gemm<<<dim3(32, 16), 256, 0, stream>>>(agg, W1, c1parts, 2048, 4096);
  skinny_gemm_a1<<<dim3(32, 8), 256, 0, stream>>>(c1parts, b1, W2, c2parts, 2048, 2048);
  logits2<<<32, 256, 0, stream>>>(c2parts, b2, W3, b3, out);
}

// Round 13
// 538.813 us; speedup vs baseline: 1.1402x; 1.1402x over previous
//
#include <hip/hip_runtime.h>
#include <hip/hip_bf16.h>
#include <stdint.h>

// Shapes: B=32, L=256, D=1024, ALIGN=1024, FF=2048, NC=3
// Precision plan:
//  - F proj (split bf16x3), E scores (split bf16x3): the softmax-sensitive path
//  - attn, betas/alphas: fp16 single, V = tanh(Cat@W_G): fp16 single + colsum
//  - classifier: fp32 VALU skinny GEMM
// All four MFMA GEMMs use the ring/counted-vmcnt schedule family.
// (Round 13 = revert to the round-11 best-measured configuration, 543.4 us;
//  round-12's fused softmax-transpose had a 512B-strided 8B scatter store and
//  prep's merged W-transpose cut occupancy — net regression.)

typedef __attribute__((ext_vector_type(8))) short    short8_t;   // 8 bf16
typedef __attribute__((ext_vector_type(4))) float    float4_t;
typedef __attribute__((ext_vector_type(8))) _Float16 half8_t;
typedef __attribute__((ext_vector_type(4))) _Float16 half4_t;
typedef __attribute__((ext_vector_type(2))) _Float16 half2_t;

#define DEVI static __device__ __forceinline__

DEVI short f2bf(float f) {
  union { float f; unsigned u; } v; v.f = f;
  unsigned r = v.u + 0x7fffu + ((v.u >> 16) & 1u);   // RNE
  return (short)(r >> 16);
}
DEVI float bf2f(short s) {
  union { unsigned u; float f; } v;
  v.u = ((unsigned)(unsigned short)s) << 16;
  return v.f;
}
DEVI void split2(float x, short& hi, short& lo) {
  hi = f2bf(x);
  lo = f2bf(x - bf2f(hi));
}
DEVI float fast_tanh(float x) {
  float e = __expf(2.0f * x);
  return 1.0f - 2.0f / (e + 1.0f);
}
DEVI void gload16(const void* g, void* l) {
  // async global->LDS, 16B/lane; LDS dest = wave-uniform base + lane*16
  __builtin_amdgcn_global_load_lds(
      (const __attribute__((address_space(1))) void*)g,
      (__attribute__((address_space(3))) void*)l, 16, 0, 0);
}

// ---------------------------------------------------------------------------
// F-projection GEMM: split-bf16x3 NT, 128x256 tile, 512 threads = 8 waves
// (2M x 4N), BK=32, ring-3 LDS (3 x 48 KiB), tile t+2 staged during tile t,
// ONE barrier per tile, counted vmcnt(6), single tail vmcnt(0).
// LDS buffer (shorts): flat 768 row-planes of 32:
//   [0,128)=Ah rows, [128,256)=Al, [256,512)=Bh, [512,768)=Bl
// Chunk swizzle: source chunk (l&3)^((l>>3)&3) => slot s of row r holds
// chunk s^((r>>1)&3); reads at slot q^((m15>>1)&3).
// Block swizzle: by = id&3 -> 4 consecutive blocks share the A panel (L2).
// Epilogue: tanh + split2 store to F_h/F_l [16384][1024].
// ---------------------------------------------------------------------------
__global__ __launch_bounds__(512, 2) void gemm_split_f(
    const short* __restrict__ Ah, const short* __restrict__ Al,
    const short* __restrict__ Bh, const short* __restrict__ Bl,
    short* __restrict__ Fh, short* __restrict__ Fl)
{
  __shared__ __align__(16) short LDS[3][24576];   // 3 x 48 KiB

  const int id   = blockIdx.x;
  const int row0 = (id >> 2) * 128;               // over M=16384
  const int col0 = (id & 3) * 256;                // over N=1024
  const int tid  = threadIdx.x;
  const int lane = tid & 63, wave = tid >> 6;
  const int wr = wave >> 2, wc = wave & 3;        // 2 M-waves x 4 N-waves
  const int m15 = lane & 15, q = lane >> 4;
  const int nt = 1024 / 32;                       // 32 K-tiles

  const int cg = ((lane & 3) ^ ((lane >> 3) & 3)) * 8;
  const short* gptr[6];
  int ldsoff[6];
#pragma unroll
  for (int c = 0; c < 6; ++c) {
    const int f0 = wave * 96 + c * 16;
    const int fr = f0 + (lane >> 2);
    const short* base;
    size_t roff;
    if (f0 < 128)      { base = Ah; roff = (size_t)(row0 + fr) * 1024; }
    else if (f0 < 256) { base = Al; roff = (size_t)(row0 + fr - 128) * 1024; }
    else if (f0 < 512) { base = Bh; roff = (size_t)(col0 + fr - 256) * 1024; }
    else               { base = Bl; roff = (size_t)(col0 + fr - 512) * 1024; }
    gptr[c]   = base + roff + cg;
    ldsoff[c] = f0 * 32;
  }
  auto stage = [&](short* slotbase, int kt) {
#pragma unroll
    for (int c = 0; c < 6; ++c)
      gload16(gptr[c] + kt * 32, slotbase + ldsoff[c]);
  };

  const int xq = (q ^ ((m15 >> 1) & 3)) * 8;
  int arow[4], brow[4];
#pragma unroll
  for (int i = 0; i < 4; ++i) {
    arow[i] = (wr * 64 + i * 16 + m15) * 32 + xq;          // Ah base 0, Al +4096
    brow[i] = 8192 + (wc * 64 + i * 16 + m15) * 32 + xq;   // Bh base, Bl +8192
  }

  float4_t acc[4][4];
#pragma unroll
  for (int i = 0; i < 4; ++i)
#pragma unroll
    for (int j = 0; j < 4; ++j) acc[i][j] = (float4_t)0.0f;

  stage(&LDS[0][0], 0);
  stage(&LDS[1][0], 1);
  asm volatile("s_waitcnt vmcnt(6)");
  __builtin_amdgcn_s_barrier();

  int cur = 0, st2 = 2;
  for (int t = 0; t < nt; ++t) {
    short* buf = &LDS[cur][0];
    __builtin_amdgcn_sched_barrier(0);

    short8_t ah[4], al[4], bh[4], bl[4];
#pragma unroll
    for (int i = 0; i < 4; ++i) {
      ah[i] = *(const short8_t*)&buf[arow[i]];
      al[i] = *(const short8_t*)&buf[arow[i] + 4096];
    }
#pragma unroll
    for (int j = 0; j < 4; ++j) {
      bh[j] = *(const short8_t*)&buf[brow[j]];
      bl[j] = *(const short8_t*)&buf[brow[j] + 8192];
    }

    if (t + 2 < nt) stage(&LDS[st2][0], t + 2);

    __builtin_amdgcn_s_setprio(1);
#pragma unroll
    for (int i = 0; i < 4; ++i)
#pragma unroll
      for (int j = 0; j < 4; ++j) {
        acc[i][j] = __builtin_amdgcn_mfma_f32_16x16x32_bf16(ah[i], bh[j], acc[i][j], 0, 0, 0);
        acc[i][j] = __builtin_amdgcn_mfma_f32_16x16x32_bf16(ah[i], bl[j], acc[i][j], 0, 0, 0);
        acc[i][j] = __builtin_amdgcn_mfma_f32_16x16x32_bf16(al[i], bh[j], acc[i][j], 0, 0, 0);
      }
    __builtin_amdgcn_s_setprio(0);

    __builtin_amdgcn_sched_barrier(0);
    if (t + 2 < nt) {
      asm volatile("s_waitcnt vmcnt(6)");
    } else if (t + 1 < nt) {
      asm volatile("s_waitcnt vmcnt(0)");
    }
    __builtin_amdgcn_s_barrier();
    cur = (cur == 2) ? 0 : cur + 1;
    st2 = (st2 == 2) ? 0 : st2 + 1;
  }

#pragma unroll
  for (int i = 0; i < 4; ++i) {
#pragma unroll
    for (int r = 0; r < 4; ++r) {
      const int gm = row0 + wr * 64 + i * 16 + q * 4 + r;
#pragma unroll
      for (int j = 0; j < 4; ++j) {
        const int gn = col0 + wc * 64 + j * 16 + m15;
        float v = fast_tanh(acc[i][j][r]);
        short hi, lo; split2(v, hi, lo);
        Fh[(size_t)gm * 1024 + gn] = hi;
        Fl[(size_t)gm * 1024 + gn] = lo;
      }
    }
  }
}

// ---------------------------------------------------------------------------
// E-scores GEMM: same ring-3 body as gemm_split_f, nt=8. Grid 256 blocks:
// zb = id>>3 (batch), sp = (id>>2)&1 (M-half), zk = id&3 (k-slice).
// Epilogue: plain fp32 store to eparts panel (zb*4+zk) [256][256].
// ---------------------------------------------------------------------------
__global__ __launch_bounds__(512, 2) void gemm_split_e(
    const short* __restrict__ Fh, const short* __restrict__ Fl,
    float* __restrict__ eparts)
{
  __shared__ __align__(16) short LDS[3][24576];

  const int id = blockIdx.x;
  const int zb = id >> 3;
  const int sp = (id >> 2) & 1;
  const int zk = id & 3;
  const int arow0 = zb * 256 + sp * 128;
  const int brow0 = 8192 + zb * 256;
  const int kbeg  = zk * 256;
  const int tid = threadIdx.x, lane = tid & 63, wave = tid >> 6;
  const int wr = wave >> 2, wc = wave & 3;
  const int m15 = lane & 15, q = lane >> 4;
  const int nt = 8;

  const int cg = ((lane & 3) ^ ((lane >> 3) & 3)) * 8;
  const short* gptr[6];
  int ldsoff[6];
#pragma unroll
  for (int c = 0; c < 6; ++c) {
    const int f0 = wave * 96 + c * 16;
    const int fr = f0 + (lane >> 2);
    const short* base;
    size_t roff;
    if (f0 < 128)      { base = Fh; roff = (size_t)(arow0 + fr) * 1024; }
    else if (f0 < 256) { base = Fl; roff = (size_t)(arow0 + fr - 128) * 1024; }
    else if (f0 < 512) { base = Fh; roff = (size_t)(brow0 + fr - 256) * 1024; }
    else               { base = Fl; roff = (size_t)(brow0 + fr - 512) * 1024; }
    gptr[c]   = base + roff + kbeg + cg;
    ldsoff[c] = f0 * 32;
  }
  auto stage = [&](short* slotbase, int kt) {
#pragma unroll
    for (int c = 0; c < 6; ++c)
      gload16(gptr[c] + kt * 32, slotbase + ldsoff[c]);
  };

  const int xq = (q ^ ((m15 >> 1) & 3)) * 8;
  int arow[4], brow[4];
#pragma unroll
  for (int i = 0; i < 4; ++i) {
    arow[i] = (wr * 64 + i * 16 + m15) * 32 + xq;
    brow[i] = 8192 + (wc * 64 + i * 16 + m15) * 32 + xq;
  }

  float4_t acc[4][4];
#pragma unroll
  for (int i = 0; i < 4; ++i)
#pragma unroll
    for (int j = 0; j < 4; ++j) acc[i][j] = (float4_t)0.0f;

  stage(&LDS[0][0], 0);
  stage(&LDS[1][0], 1);
  asm volatile("s_waitcnt vmcnt(6)");
  __builtin_amdgcn_s_barrier();

  int cur = 0, st2 = 2;
  for (int t = 0; t < nt; ++t) {
    short* buf = &LDS[cur][0];
    __builtin_amdgcn_sched_barrier(0);

    short8_t ah[4], al[4], bh[4], bl[4];
#pragma unroll
    for (int i = 0; i < 4; ++i) {
      ah[i] = *(const short8_t*)&buf[arow[i]];
      al[i] = *(const short8_t*)&buf[arow[i] + 4096];
    }
#pragma unroll
    for (int j = 0; j < 4; ++j) {
      bh[j] = *(const short8_t*)&buf[brow[j]];
      bl[j] = *(const short8_t*)&buf[brow[j] + 8192];
    }

    if (t + 2 < nt) stage(&LDS[st2][0], t + 2);

    __builtin_amdgcn_s_setprio(1);
#pragma unroll
    for (int i = 0; i < 4; ++i)
#pragma unroll
      for (int j = 0; j < 4; ++j) {
        acc[i][j] = __builtin_amdgcn_mfma_f32_16x16x32_bf16(ah[i], bh[j], acc[i][j], 0, 0, 0);
        acc[i][j] = __builtin_amdgcn_mfma_f32_16x16x32_bf16(ah[i], bl[j], acc[i][j], 0, 0, 0);
        acc[i][j] = __builtin_amdgcn_mfma_f32_16x16x32_bf16(al[i], bh[j], acc[i][j], 0, 0, 0);
      }
    __builtin_amdgcn_s_setprio(0);

    __builtin_amdgcn_sched_barrier(0);
    if (t + 2 < nt) {
      asm volatile("s_waitcnt vmcnt(6)");
    } else if (t + 1 < nt) {
      asm volatile("s_waitcnt vmcnt(0)");
    }
    __builtin_amdgcn_s_barrier();
    cur = (cur == 2) ? 0 : cur + 1;
    st2 = (st2 == 2) ? 0 : st2 + 1;
  }

  float* ep = eparts + (size_t)(zb * 4 + zk) * 65536;
#pragma unroll
  for (int i = 0; i < 4; ++i) {
#pragma unroll
    for (int r = 0; r < 4; ++r) {
      const int gm = sp * 128 + wr * 64 + i * 16 + q * 4 + r;
#pragma unroll
      for (int j = 0; j < 4; ++j) {
        const int gn = wc * 64 + j * 16 + m15;
        ep[(size_t)gm * 256 + gn] = acc[i][j][r];
      }
    }
  }
}

// ---------------------------------------------------------------------------
// betas/alphas GEMM: fp16 NT ring-3, 128x256 tile, 512 threads, BK=32,
// 3 x 24 KiB LDS, counted vmcnt(3), nt=8.
// grid (8,1,64): A = attn[z] (z<32) / attnT (z>=32, contiguous);
// B = PHbT[(z^32)] panel. Epilogue: fp16 store to Cat right halves.
// ---------------------------------------------------------------------------
__global__ __launch_bounds__(512, 2) void gemm_f16r(
    const _Float16* __restrict__ attn, const _Float16* __restrict__ phbt,
    _Float16* __restrict__ cat)
{
  __shared__ __align__(16) _Float16 LDS[3][12288];   // 3 x 24 KiB

  const int bx = blockIdx.x;
  const int z  = blockIdx.z;
  const int mt = bx >> 2, ntile = bx & 3;
  const int row0 = mt * 128;
  const int col0 = ntile * 256;
  const _Float16* A = attn + (size_t)z * 65536;
  const _Float16* B = phbt + (size_t)(z ^ 32) * 262144 + (size_t)col0 * 256;
  const int tid = threadIdx.x, lane = tid & 63, wave = tid >> 6;
  const int wr = wave >> 2, wc = wave & 3;
  const int m15 = lane & 15, q = lane >> 4;
  const int nt = 8;

  const int cg = ((lane & 3) ^ ((lane >> 3) & 3)) * 8;
  const _Float16* gptr[3];
  int ldsoff[3];
#pragma unroll
  for (int c = 0; c < 3; ++c) {
    const int f0 = wave * 48 + c * 16;
    const int fr = f0 + (lane >> 2);
    if (f0 < 128) gptr[c] = A + (size_t)(row0 + fr) * 256 + cg;
    else          gptr[c] = B + (size_t)(fr - 128) * 256 + cg;
    ldsoff[c] = f0 * 32;
  }
  auto stage = [&](_Float16* slotbase, int kt) {
#pragma unroll
    for (int c = 0; c < 3; ++c)
      gload16(gptr[c] + kt * 32, slotbase + ldsoff[c]);
  };

  const int xq = (q ^ ((m15 >> 1) & 3)) * 8;
  int aoff[4], boff[4];
#pragma unroll
  for (int i = 0; i < 4; ++i) {
    aoff[i] = (wr * 64 + i * 16 + m15) * 32 + xq;
    boff[i] = (128 + wc * 64 + i * 16 + m15) * 32 + xq;
  }

  float4_t acc[4][4];
#pragma unroll
  for (int i = 0; i < 4; ++i)
#pragma unroll
    for (int j = 0; j < 4; ++j) acc[i][j] = (float4_t)0.0f;

  stage(&LDS[0][0], 0);
  stage(&LDS[1][0], 1);
  asm volatile("s_waitcnt vmcnt(3)");
  __builtin_amdgcn_s_barrier();

  int cur = 0, st2 = 2;
  for (int t = 0; t < nt; ++t) {
    _Float16* buf = &LDS[cur][0];
    __builtin_amdgcn_sched_barrier(0);

    half8_t af[4], bf[4];
#pragma unroll
    for (int i = 0; i < 4; ++i) af[i] = *(const half8_t*)&buf[aoff[i]];
#pragma unroll
    for (int j = 0; j < 4; ++j) bf[j] = *(const half8_t*)&buf[boff[j]];

    if (t + 2 < nt) stage(&LDS[st2][0], t + 2);

    __builtin_amdgcn_s_setprio(1);
#pragma unroll
    for (int i = 0; i < 4; ++i)
#pragma unroll
      for (int j = 0; j < 4; ++j)
        acc[i][j] = __builtin_amdgcn_mfma_f32_16x16x32_f16(af[i], bf[j], acc[i][j], 0, 0, 0);
    __builtin_amdgcn_s_setprio(0);

    __builtin_amdgcn_sched_barrier(0);
    if (t + 2 < nt) {
      asm volatile("s_waitcnt vmcnt(3)");
    } else if (t + 1 < nt) {
      asm volatile("s_waitcnt vmcnt(0)");
    }
    __builtin_amdgcn_s_barrier();
    cur = (cur == 2) ? 0 : cur + 1;
    st2 = (st2 == 2) ? 0 : st2 + 1;
  }

  _Float16* Cp = cat + 1024 + (size_t)z * (256 * 2048);
#pragma unroll
  for (int i = 0; i < 4; ++i) {
#pragma unroll
    for (int r = 0; r < 4; ++r) {
      const int gm = row0 + wr * 64 + i * 16 + q * 4 + r;
#pragma unroll
      for (int j = 0; j < 4; ++j) {
        const int gn = col0 + wc * 64 + j * 16 + m15;
        Cp[(size_t)gm * 2048 + gn] = (_Float16)acc[i][j][r];
      }
    }
  }
}

// ---------------------------------------------------------------------------
// V-GEMM: fp16 NT, 256x256 tile, BK=32, 512 threads = 8 waves (2M x 4N),
// 4-deep LDS ring (4 x 32 KiB), tile t+2 staged during tile t, ONE barrier
// per K-tile, counted vmcnt(4). Conflict-free chunk swizzle (0 measured).
// Fused tanh + column-sum epilogue -> agg. (141-165 us machine band.)
// ---------------------------------------------------------------------------
__global__ __launch_bounds__(512, 2) void gemm_f16_sum8(
    const _Float16* __restrict__ A, int lda,
    const _Float16* __restrict__ B, int ldb,
    int K, float* __restrict__ agg)
{
  __shared__ __align__(16) _Float16 LDS[4][2 * 256 * 32];

  const int row0 = blockIdx.x * 256;
  const int col0 = blockIdx.y * 256;
  const int tid  = threadIdx.x;
  const int lane = tid & 63, wave = tid >> 6;
  const int wr = wave >> 2, wc = wave & 3;     // 2 M-waves x 4 N-waves
  const int m15 = lane & 15, q = lane >> 4;
  const int nt = K / 32;

  const int srow = wave * 32 + (lane >> 2);
  const int cg   = ((lane & 3) ^ ((lane >> 3) & 3)) * 8;
  const _Float16* gA = A + (size_t)(row0 + srow) * lda + cg;
  const _Float16* gB = B + (size_t)(col0 + srow) * ldb + cg;

  auto stageA = [&](int t) {
    const _Float16* g = gA + t * 32;
    _Float16* l = &LDS[t & 3][wave * 1024];
    gload16(g, l);
    gload16(g + (size_t)16 * lda, l + 512);
  };
  auto stageB = [&](int t) {
    const _Float16* g = gB + t * 32;
    _Float16* l = &LDS[t & 3][8192 + wave * 1024];
    gload16(g, l);
    gload16(g + (size_t)16 * ldb, l + 512);
  };

  const int xq = (q ^ ((m15 >> 1) & 3)) * 8;
  int aoff[8], boff[4];
#pragma unroll
  for (int i = 0; i < 8; ++i)
    aoff[i] = (wr * 128 + i * 16 + m15) * 32 + xq;
#pragma unroll
  for (int j = 0; j < 4; ++j)
    boff[j] = 8192 + (wc * 64 + j * 16 + m15) * 32 + xq;

  float4_t acc[8][4];
#pragma unroll
  for (int i = 0; i < 8; ++i)
#pragma unroll
    for (int j = 0; j < 4; ++j) acc[i][j] = (float4_t)0.0f;

  stageA(0); stageB(0);
  stageA(1); stageB(1);
  asm volatile("s_waitcnt vmcnt(4)");
  __builtin_amdgcn_s_barrier();

  for (int t = 0; t < nt; ++t) {
    const _Float16* buf = &LDS[t & 3][0];
    __builtin_amdgcn_sched_barrier(0);

    half8_t a0[4], a1[4], bb[4];
#pragma unroll
    for (int i = 0; i < 4; ++i) a0[i] = *(const half8_t*)&buf[aoff[i]];
#pragma unroll
    for (int j = 0; j < 4; ++j) bb[j] = *(const half8_t*)&buf[boff[j]];
#pragma unroll
    for (int i = 0; i < 4; ++i) a1[i] = *(const half8_t*)&buf[aoff[4 + i]];

    if (t + 2 < nt) { stageA(t + 2); stageB(t + 2); }

    __builtin_amdgcn_s_setprio(1);
#pragma unroll
    for (int i = 0; i < 4; ++i)
#pragma unroll
      for (int j = 0; j < 4; ++j)
        acc[i][j] = __builtin_amdgcn_mfma_f32_16x16x32_f16(a0[i], bb[j], acc[i][j], 0, 0, 0);
#pragma unroll
    for (int i = 0; i < 4; ++i)
#pragma unroll
      for (int j = 0; j < 4; ++j)
        acc[4 + i][j] = __builtin_amdgcn_mfma_f32_16x16x32_f16(a1[i], bb[j], acc[4 + i][j], 0, 0, 0);
    __builtin_amdgcn_s_setprio(0);

    __builtin_amdgcn_sched_barrier(0);
    if (t + 2 < nt) {
      asm volatile("s_waitcnt vmcnt(4)");
    } else if (t + 1 < nt) {
      asm volatile("s_waitcnt vmcnt(0)");
    }
    __builtin_amdgcn_s_barrier();
  }

  // ---- epilogue: tanh + column-sum -> agg[b][half*2048 + col] ----
  const int half_ = row0 >= 8192;
  const int b     = (row0 & 8191) >> 8;
#pragma unroll
  for (int j = 0; j < 4; ++j) {
    float s = 0.0f;
#pragma unroll
    for (int i = 0; i < 8; ++i)
#pragma unroll
      for (int r = 0; r < 4; ++r) s += fast_tanh(acc[i][j][r]);
    s += __shfl_xor(s, 16);
    s += __shfl_xor(s, 32);
    if (q == 0) {
      int col = col0 + wc * 64 + j * 16 + m15;
      atomicAdd(&agg[(size_t)b * 4096 + half_ * 2048 + col], s);
    }
  }
}

// ---------------------------------------------------------------------------
// Merged weight transpose: blocks 0..1023 = W_F [1024][1024] -> split bf16
// transpose; blocks 1024..5119 = W_G [2048][2048] -> fp16 transpose.
// ---------------------------------------------------------------------------
__global__ __launch_bounds__(256) void transpose_w(
    const float* __restrict__ WF, short* __restrict__ oh, short* __restrict__ ol,
    const float* __restrict__ WG, _Float16* __restrict__ og)
{
  __shared__ float tile[32][33];
  const int id = blockIdx.x;
  const int tx = threadIdx.x & 31, ty = threadIdx.x >> 5;
  if (id < 1024) {
    const int c0 = (id & 31) * 32, r0 = (id >> 5) * 32;   // over [1024][1024]
#pragma unroll
    for (int i = 0; i < 4; ++i) {
      int r = ty + i * 8;
      tile[r][tx] = WF[(size_t)(r0 + r) * 1024 + c0 + tx];
    }
    __syncthreads();
#pragma unroll
    for (int i = 0; i < 4; ++i) {
      int cc = ty + i * 8;
      float v = tile[tx][cc];
      short hi, lo; split2(v, hi, lo);
      size_t o = (size_t)(c0 + cc) * 1024 + r0 + tx;
      oh[o] = hi;
      ol[o] = lo;
    }
  } else {
    const int t2 = id - 1024;
    const int c0 = (t2 & 63) * 32, r0 = (t2 >> 6) * 32;   // over [2048][2048]
#pragma unroll
    for (int i = 0; i < 4; ++i) {
      int r = ty + i * 8;
      tile[r][tx] = WG[(size_t)(r0 + r) * 2048 + c0 + tx];
    }
    __syncthreads();
#pragma unroll
    for (int i = 0; i < 4; ++i) {
      int cc = ty + i * 8;
      og[(size_t)(c0 + cc) * 2048 + r0 + tx] = (_Float16)tile[tx][cc];
    }
  }
}

// --- fp16 [256x256] batched transpose (attn -> attnT) ---
__global__ __launch_bounds__(256) void transpose_b2b(
    const short* __restrict__ in, short* __restrict__ out,
    int R, int C, long sIn, long sOut)
{
  __shared__ short tile[32][33];
  in  += (size_t)blockIdx.z * sIn;
  out += (size_t)blockIdx.z * sOut;
  const int tx = threadIdx.x & 31, ty = threadIdx.x >> 5;
  const int c0 = blockIdx.x * 32, r0 = blockIdx.y * 32;
#pragma unroll
  for (int i = 0; i < 4; ++i) {
    int r = ty + i * 8;
    tile[r][tx] = in[(size_t)(r0 + r) * C + c0 + tx];
  }
  __syncthreads();
#pragma unroll
  for (int i = 0; i < 4; ++i) {
    int cc = ty + i * 8;
    out[(size_t)(c0 + cc) * R + r0 + tx] = tile[tx][cc];
  }
}

// ---------------------------------------------------------------------------
// Fused input conversion + transpose, vectorized. One pass over P/H producing
// (a) split bf16 planes, (b) fp16 Cat left half, (c) fp16 per-batch transpose
// PHbT[z][1024][256] (z<32 = P^T, z>=32 = H^T). Also zeros agg (512 KB) as a
// side task of the first 128 blocks.
// grid (16, 4, 64): x = 64-col tile over 1024, y = 64-row tile over 256.
// ---------------------------------------------------------------------------
__global__ __launch_bounds__(256) void conv_in_t(
    const float* __restrict__ P, const float* __restrict__ Hh,
    short* __restrict__ oh, short* __restrict__ ol,
    _Float16* __restrict__ cat, _Float16* __restrict__ phbt,
    float* __restrict__ agg)
{
  __shared__ __align__(16) float tile[64][68];   // 272B rows, 16B-aligned
  const int zb   = blockIdx.z;
  const int half = zb >> 5, b = zb & 31;
  const int bid = (zb * 4 + blockIdx.y) * 16 + blockIdx.x;
  if (bid < 128) {
    float4_t zz = (float4_t)0.0f;
    *(float4_t*)&agg[(size_t)bid * 1024 + threadIdx.x * 4] = zz;
  }
  const float* in = (half ? Hh : P) + (size_t)b * 256 * 1024;
  const int c0 = blockIdx.x * 64;   // col in [0,1024)
  const int r0 = blockIdx.y * 64;   // row in [0,256)
  const int t  = threadIdx.x;
  const int rl = t >> 4;            // 0..15
  const int c4 = (t & 15) * 4;      // 0,4,...,60
  const size_t rowbase = (size_t)half * 8192 + (size_t)b * 256;
#pragma unroll
  for (int i = 0; i < 4; ++i) {
    int r = rl + i * 16;
    float4 v = *(const float4*)&in[(size_t)(r0 + r) * 1024 + c0 + c4];
    *(float4*)&tile[r][c4] = v;
    short4 h, l;
    split2(v.x, h.x, l.x); split2(v.y, h.y, l.y);
    split2(v.z, h.z, l.z); split2(v.w, h.w, l.w);
    size_t o = (rowbase + r0 + r) * 1024 + c0 + c4;
    *(short4*)&oh[o] = h;
    *(short4*)&ol[o] = l;
    half4_t c16;
    c16.x = (_Float16)v.x; c16.y = (_Float16)v.y;
    c16.z = (_Float16)v.z; c16.w = (_Float16)v.w;
    *(half4_t*)&cat[(rowbase + r0 + r) * 2048 + c0 + c4] = c16;
  }
  __syncthreads();
  _Float16* op = phbt + (size_t)zb * 1024 * 256;
  const int tx = t & 31;            // row-pair index: rows 2tx, 2tx+1
  const int w  = t >> 5;            // 0..7
#pragma unroll
  for (int i = 0; i < 8; ++i) {
    int cc = w + i * 8;             // 0..63
    half2_t p;
    p.x = (_Float16)tile[tx * 2][cc];
    p.y = (_Float16)tile[tx * 2 + 1][cc];
    *(half2_t*)&op[(size_t)(c0 + cc) * 256 + r0 + tx * 2] = p;
  }
}

// --- softmax over rows of 256, summing 4 E split-K slice panels,
//     fp32 -> fp16. eparts layout: [zb*4+zk][256][256]. ---
__global__ __launch_bounds__(256) void softmax_rows(
    const float* __restrict__ e, _Float16* __restrict__ attn)
{
  const int row  = blockIdx.x * 4 + (threadIdx.x >> 6);   // 0..8191
  const int lane = threadIdx.x & 63;
  const size_t base = ((size_t)(row >> 8) * 4) * 65536
                    + (size_t)(row & 255) * 256 + lane * 4;
  const float4 v0 = *(const float4*)&e[base];
  const float4 v1 = *(const float4*)&e[base + 65536];
  const float4 v2 = *(const float4*)&e[base + 2 * 65536];
  const float4 v3 = *(const float4*)&e[base + 3 * 65536];
  float4 v;
  v.x = (v0.x + v1.x) + (v2.x + v3.x);
  v.y = (v0.y + v1.y) + (v2.y + v3.y);
  v.z = (v0.z + v1.z) + (v2.z + v3.z);
  v.w = (v0.w + v1.w) + (v2.w + v3.w);
  float m = fmaxf(fmaxf(v.x, v.y), fmaxf(v.z, v.w));
#pragma unroll
  for (int off = 32; off; off >>= 1) m = fmaxf(m, __shfl_xor(m, off));
  float e0 = __expf(v.x - m), e1 = __expf(v.y - m);
  float e2 = __expf(v.z - m), e3 = __expf(v.w - m);
  float s = e0 + e1 + e2 + e3;
#pragma unroll
  for (int off = 32; off; off >>= 1) s += __shfl_xor(s, off);
  float inv = 1.0f / s;
  half4_t o;
  o.x = (_Float16)(e0 * inv); o.y = (_Float16)(e1 * inv);
  o.z = (_Float16)(e2 * inv); o.w = (_Float16)(e3 * inv);
  *(half4_t*)&attn[(size_t)row * 256 + lane * 4] = o;
}

// ---------------------------------------------------------------------------
// Skinny fp32 GEMM, split-K per-slice panels (no atomics, no pre-zero):
// outp[slice][32][N] = A[32][k-slice] @ B[k-slice][N].
// grid (N/64, K/256); block 256. A-slice transposed in LDS [k][m] (+1 pad).
// ---------------------------------------------------------------------------
__global__ __launch_bounds__(256) void skinny_gemm(
    const float* __restrict__ A, const float* __restrict__ B,
    float* __restrict__ outp, int N, int K)
{
  __shared__ float Asl[256][33];
  const int n0 = blockIdx.x * 64;
  const int k0 = blockIdx.y * 256;
  const int t  = threadIdx.x;
#pragma unroll
  for (int j = 0; j < 32; ++j) {
    Asl[t][j] = A[(size_t)j * K + k0 + t];
  }
  __syncthreads();
  const int l = t & 63, w = t >> 6;
  const int n = n0 + l;
  float acc[8] = {0.f, 0.f, 0.f, 0.f, 0.f, 0.f, 0.f, 0.f};
  const float* Bp = B + (size_t)k0 * N + n;
#pragma unroll 4
  for (int k = 0; k < 256; ++k) {
    float bv = Bp[(size_t)k * N];
#pragma unroll
    for (int m = 0; m < 8; ++m)
      acc[m] += Asl[k][w * 8 + m] * bv;
  }
  float* o = outp + (size_t)blockIdx.y * 32 * N;
#pragma unroll
  for (int m = 0; m < 8; ++m)
    o[(size_t)(w * 8 + m) * N + n] = acc[m];
}

// --- a1 = tanh(sum_slices(parts) + bias), fp32 out ---
__global__ __launch_bounds__(256) void bias_sum_tanh(
    const float* __restrict__ parts, int nslice,
    const float* __restrict__ bias, float* __restrict__ o, int n)
{
  int i = blockIdx.x * 256 + threadIdx.x;
  if (i < n) {
    float s = 0.0f;
    for (int sl = 0; sl < nslice; ++sl) s += parts[(size_t)sl * n + i];
    o[i] = fast_tanh(s + bias[i & 2047]);
  }
}

// --- logits: out[b][0..2] = tanh(sum_8slices(c2parts)[b]+b2) @ W3 + b3 ---
__global__ __launch_bounds__(256) void logits2(
    const float* __restrict__ c2parts, const float* __restrict__ b2,
    const float* __restrict__ W3, const float* __restrict__ b3,
    float* __restrict__ out)
{
  const int b = blockIdx.x, t = threadIdx.x;
  float p0 = 0.f, p1 = 0.f, p2 = 0.f;
  for (int k = t; k < 2048; k += 256) {
    float c = 0.0f;
#pragma unroll
    for (int sl = 0; sl < 8; ++sl) c += c2parts[(size_t)sl * 65536 + b * 2048 + k];
    float a = fast_tanh(c + b2[k]);
    p0 += a * W3[k * 3 + 0];
    p1 += a * W3[k * 3 + 1];
    p2 += a * W3[k * 3 + 2];
  }
#pragma unroll
  for (int off = 32; off; off >>= 1) {
    p0 += __shfl_xor(p0, off);
    p1 += __shfl_xor(p1, off);
    p2 += __shfl_xor(p2, off);
  }
  __shared__ float red[4][3];
  if ((t & 63) == 0) {
    red[t >> 6][0] = p0; red[t >> 6][1] = p1; red[t >> 6][2] = p2;
  }
  __syncthreads();
  if (t < 3) out[b * 3 + t] = b3[t] + red[0][t] + red[1][t] + red[2][t] + red[3][t];
}

extern "C" void kernel_launch(void* const* d_in, const int* in_sizes, int n_in,
                              void* d_out, int out_size, void* d_ws, size_t ws_size,
                              hipStream_t stream) {
  (void)in_sizes; (void)n_in; (void)out_size; (void)ws_size;
  const float* P   = (const float*)d_in[0];
  const float* H   = (const float*)d_in[1];
  const float* W_F = (const float*)d_in[2];
  const float* W_G = (const float*)d_in[3];
  const float* W1  = (const float*)d_in[4];
  const float* b1  = (const float*)d_in[5];
  const float* W2  = (const float*)d_in[6];
  const float* b2  = (const float*)d_in[7];
  const float* W3  = (const float*)d_in[8];
  const float* b3  = (const float*)d_in[9];
  float* out = (float*)d_out;

  char* wsp = (char*)d_ws;
  auto alloc = [&](size_t bytes) {
    char* p = wsp;
    wsp += (bytes + 255) & ~(size_t)255;
    return p;
  };
  short*    Pp_h  = (short*)alloc(16384ull * 1024 * 2);     // [P;H] split planes
  short*    Pp_l  = (short*)alloc(16384ull * 1024 * 2);
  _Float16* Cat16 = (_Float16*)alloc(16384ull * 2048 * 2);  // [P|betas ; H|alphas]
  short*    Fbuf  = (short*)alloc(32ull * 1024 * 1024 * 2); // 64 MB: F planes
  _Float16* PHbT  = (_Float16*)alloc(64ull * 1024 * 256 * 2); // 32 MB: P^T|H^T fp16
  short*    WFT_h = (short*)alloc(1024ull * 1024 * 2);
  short*    WFT_l = (short*)alloc(1024ull * 1024 * 2);
  _Float16* WGT16 = (_Float16*)alloc(2048ull * 2048 * 2);
  _Float16* attn  = (_Float16*)alloc(32ull * 256 * 256 * 2);
  _Float16* attnT = (_Float16*)alloc(32ull * 256 * 256 * 2);
  float*    agg   = (float*)alloc(32ull * 4096 * 4);
  float*    a1f   = (float*)alloc(32ull * 2048 * 4);

  short* F_h = Fbuf;
  short* F_l = Fbuf + 16384ull * 1024;
  // Aliases into Pp planes (dead after the F-projection, step 2):
  float* eparts  = (float*)Pp_h;                       // 32 MB <= 33.5 MB
  float* c1parts = (float*)Pp_l;                       // 16 x 32 x 2048 fp32
  float* c2parts = (float*)(Pp_l + 4ull * 1024 * 1024);// 8 x 32 x 2048 fp32

  // 1. fused input conversion + per-batch transpose (+agg zero); W transposes
  conv_in_t<<<dim3(16, 4, 64), 256, 0, stream>>>(P, H, Pp_h, Pp_l, Cat16, PHbT, agg);
  transpose_w<<<5120, 256, 0, stream>>>(W_F, WFT_h, WFT_l, W_G, WGT16);

  // 2. F = tanh([P;H] @ W_F), split bf16x3, ring-3 counted-vmcnt kernel
  gemm_split_f<<<512, 512, 0, stream>>>(Pp_h, Pp_l, WFT_h, WFT_l, F_h, F_l);

  // 3. scores E[z] = F_p[z] @ F_h[z]^T, ring-3, split-K x4 slice panels
  gemm_split_e<<<256, 512, 0, stream>>>(F_h, F_l, eparts);

  // 4. softmax (sums 4 E slices) -> fp16 attn; attn^T
  softmax_rows<<<2048, 256, 0, stream>>>(eparts, attn);
  transpose_b2b<<<dim3(8, 8, 32), 256, 0, stream>>>(
      (const short*)attn, (short*)attnT, 256, 256, 65536, 65536);

  // 5. betas (z<32) and alphas (z>=32) in ONE launch, ring-3 fp16 kernel
  gemm_f16r<<<dim3(8, 1, 64), 512, 0, stream>>>(attn, PHbT, Cat16);

  // 6. V = tanh(Cat @ W_G) fused column-sum -> agg
  gemm_f16_sum8<<<dim3(64, 8, 1), 512, 0, stream>>>(
      Cat16, 2048, WGT16, 2048, 2048, agg);

  // 7. classifier: fp32 skinny split-K GEMMs, per-slice panels, no atomics
  skinny_gemm<<<dim3(32, 16), 256, 0, stream>>>(agg, W1, c1parts, 2048, 4096);
  bias_sum_tanh<<<256, 256, 0, stream>>>(c1parts, 16, b1, a1f, 32 * 2048);
  skinny_gemm<<<dim3(32, 8), 256, 0, stream>>>(a1f, W2, c2parts, 2048, 2048);
  logits2<<<32, 256, 0, stream>>>(c2parts, b2, W3, b3, out);
}